// Round 10
// baseline (177.434 us; speedup 1.0000x reference)
//
#include <hip/hip_runtime.h>
#include <math.h>

// Channelatt: x(32,256,56,56) f32 -> x * sigmoid(gate(n,c))
// DIAGNOSTIC ROUND: k1 and k5 internally repeated 4x (idempotent) so they
// exceed the 58us harness fills and surface in rocprof top-5 with counters.
// Memory clobber between reps prevents cross-rep CSE/DCE.

#define N_ 32
#define C_ 256
#define H_ 56
#define W_ 56
#define S_ 3136   // H_*W_
#define Q_ 784    // S_/4 (float4 units)
#define LN_EPS 1e-5f

#define NCH 16    // c-chunks in pass 1
#define CPC 16    // channels per chunk (NCH*CPC == C_)
#define SQ  4     // s-chunks in pass 1
#define QCH 196   // f4 per s-chunk (Q_/SQ)
#define REPS 4    // diagnostic repeat factor

using f4 = __attribute__((ext_vector_type(4))) float;

__device__ __forceinline__ float wave_sum(float v) {
  #pragma unroll
  for (int o = 32; o > 0; o >>= 1) v += __shfl_xor(v, o);
  return v;
}
__device__ __forceinline__ float wave_max(float v) {
  #pragma unroll
  for (int o = 32; o > 0; o >>= 1) v = fmaxf(v, __shfl_xor(v, o));
  return v;
}
__device__ __forceinline__ float block_sum(float v, float* red) {
  int lane = threadIdx.x & 63, wid = threadIdx.x >> 6;
  float w = wave_sum(v);
  __syncthreads();
  if (lane == 0) red[wid] = w;
  __syncthreads();
  return red[0] + red[1] + red[2] + red[3];
}
__device__ __forceinline__ float dot4(f4 a, f4 b) {
  return a.x * b.x + a.y * b.y + a.z * b.z + a.w * b.w;
}
__device__ __forceinline__ float max4(f4 a) {
  return fmaxf(fmaxf(a.x, a.y), fmaxf(a.z, a.w));
}

// K1 x4: partial logits. Block = (c-chunk, n, s-chunk) = 2048 blocks.
__global__ __launch_bounds__(256)
void k_logits_x4(const float* __restrict__ x, const float* __restrict__ gc_w,
                 float* __restrict__ lpart) {
  int ch = blockIdx.x, n = blockIdx.y, sq = blockIdx.z;
  int tid = threadIdx.x;
  int c0 = ch * CPC;
  __shared__ float gw[CPC];
  if (tid < CPC) gw[tid] = gc_w[c0 + tid];
  __syncthreads();
  if (tid >= QCH) return;
  int q = sq * QCH + tid;
  for (int rep = 0; rep < REPS; ++rep) {
    const f4* xb = (const f4*)x + ((size_t)n * C_ + c0) * Q_ + q;
    f4 A = {0,0,0,0};
    #pragma unroll
    for (int c = 0; c < CPC; ++c) A += gw[c] * xb[(size_t)c * Q_];
    ((f4*)lpart)[((size_t)n * NCH + ch) * Q_ + q] = A;
    asm volatile("" ::: "memory");   // forbid cross-rep CSE; reps re-fetch
  }
}

// K2: fold 16 partials -> softmax over s per n. One block per n, float4.
__global__ void k_softmax(const float* __restrict__ lpart, float* __restrict__ attn) {
  int n = blockIdx.x, tid = threadIdx.x;
  __shared__ float red[4];
  const f4* lp = (const f4*)lpart + (size_t)n * NCH * Q_;
  f4 v[4];
  float m = -INFINITY;
  #pragma unroll
  for (int k = 0; k < 3; ++k) {
    int q = tid + k * 256;
    f4 acc = {0,0,0,0};
    #pragma unroll
    for (int ch = 0; ch < NCH; ++ch) acc += lp[(size_t)ch * Q_ + q];
    v[k] = acc;
    m = fmaxf(m, max4(acc));
  }
  if (tid < 16) {
    f4 acc = {0,0,0,0};
    #pragma unroll
    for (int ch = 0; ch < NCH; ++ch) acc += lp[(size_t)ch * Q_ + 768 + tid];
    v[3] = acc;
    m = fmaxf(m, max4(acc));
  } else {
    v[3] = f4{-INFINITY, -INFINITY, -INFINITY, -INFINITY};
  }
  float wm = wave_max(m);
  int lane = tid & 63, wid = tid >> 6;
  if (lane == 0) red[wid] = wm;
  __syncthreads();
  m = fmaxf(fmaxf(red[0], red[1]), fmaxf(red[2], red[3]));
  float z = 0.f;
  #pragma unroll
  for (int k = 0; k < 4; ++k) {
    v[k].x = expf(v[k].x - m); v[k].y = expf(v[k].y - m);
    v[k].z = expf(v[k].z - m); v[k].w = expf(v[k].w - m);
    z += v[k].x + v[k].y + v[k].z + v[k].w;   // exp(-inf)=0 for tail lanes
  }
  z = block_sum(z, red);
  float inv = 1.f / z;
  f4* ap = (f4*)attn + (size_t)n * Q_;
  #pragma unroll
  for (int k = 0; k < 3; ++k) ap[tid + k * 256] = v[k] * inv;
  if (tid < 16) ap[768 + tid] = v[3] * inv;
}

// K3: per (n,c): x_g, x_max, x_dct in one warm x pass. Block per (c,n) = 8192.
__global__ void k_stats(const float* __restrict__ x, const float* __restrict__ attn,
                        float* __restrict__ xg, float* __restrict__ xmax,
                        float* __restrict__ xdct) {
  int c = blockIdx.x, n = blockIdx.y, tid = threadIdx.x;
  __shared__ float bh[H_];
  __shared__ f4 bw4[14];
  __shared__ float red[3][4];
  int grp = c >> 6;
  int u = grp >> 1, vv = grp & 1;
  const float invs = 0.13363062f;   // 1/sqrt(56)
  const float sq2  = 1.41421356f;
  if (tid < H_) {
    float b = cosf((float)M_PI * u * (tid + 0.5f) / H_) * invs;
    bh[tid] = u ? b * sq2 : b;
  } else if (tid >= 64 && tid < 64 + 14) {
    int j = tid - 64;
    f4 b;
    #pragma unroll
    for (int e = 0; e < 4; ++e) {
      float t = cosf((float)M_PI * vv * (4 * j + e + 0.5f) / W_) * invs;
      ((float*)&b)[e] = vv ? t * sq2 : t;
    }
    bw4[j] = b;
  }
  __syncthreads();
  const f4* xp = (const f4*)(x + ((size_t)n * C_ + c) * S_);
  const f4* ap = (const f4*)(attn + (size_t)n * S_);
  float g = 0.f, d = 0.f, mx = -INFINITY;
  #pragma unroll
  for (int k = 0; k < 3; ++k) {
    int q = tid + k * 256;
    f4 xv = xp[q], av = ap[q];
    g += dot4(xv, av);
    mx = fmaxf(max4(xv), mx);
    int h = q / 14;
    d += bh[h] * dot4(xv, bw4[q - h * 14]);
  }
  if (tid < 16) {
    int q = 768 + tid;
    f4 xv = xp[q], av = ap[q];
    g += dot4(xv, av);
    mx = fmaxf(max4(xv), mx);
    int h = q / 14;
    d += bh[h] * dot4(xv, bw4[q - h * 14]);
  }
  float gs = wave_sum(g), ms = wave_max(mx), ds = wave_sum(d);
  int lane = tid & 63, wid = tid >> 6;
  if (lane == 0) { red[0][wid] = gs; red[1][wid] = ms; red[2][wid] = ds; }
  __syncthreads();
  if (tid == 0) {
    xg[n * C_ + c]   = red[0][0] + red[0][1] + red[0][2] + red[0][3];
    xmax[n * C_ + c] = fmaxf(fmaxf(red[1][0], red[1][1]), fmaxf(red[1][2], red[1][3]));
    xdct[n * C_ + c] = red[2][0] + red[2][1] + red[2][2] + red[2][3];
  }
}

// K4: per-(n,c) gate math. One block per n, thread = channel.
__global__ void k_gate(const float* __restrict__ xg, const float* __restrict__ xmax,
                       const float* __restrict__ xdct,
                       const float* __restrict__ lc_w, const float* __restrict__ lc_b,
                       const float* __restrict__ lcln_g, const float* __restrict__ lcln_b,
                       const float* __restrict__ tw_w, const float* __restrict__ tw_b,
                       const float* __restrict__ twln_g, const float* __restrict__ twln_b,
                       const float* __restrict__ wdct, const float* __restrict__ wmax,
                       float* __restrict__ gate) {
  int n = blockIdx.x, c = threadIdx.x;
  __shared__ float xs[C_ + 2];
  __shared__ float att_s[C_];
  __shared__ float red[4];
  float g  = xg[n * C_ + c];
  float sv = wmax[c] * xmax[n * C_ + c] + wdct[c] * xdct[n * C_ + c];
  xs[c + 1] = sv;
  if (c == 0) { xs[0] = 0.f; xs[C_ + 1] = 0.f; }
  __syncthreads();
  float xl = lc_w[0] * xs[c] + lc_w[1] * xs[c + 1] + lc_w[2] * xs[c + 2] + lc_b[0];
  float t = g + sv + xl;
  float mu  = block_sum(t, red) * (1.f / C_);
  float dv  = t - mu;
  float var = block_sum(dv * dv, red) * (1.f / C_);
  float att = dv * rsqrtf(var + LN_EPS) * lcln_g[c] + lcln_b[c];
  att_s[c] = att;
  __syncthreads();
  float a2 = tw_b[c];
  const f4* wrow = (const f4*)(tw_w + c * C_);
  const f4* arow = (const f4*)att_s;
  #pragma unroll 8
  for (int k = 0; k < C_ / 4; ++k) a2 += dot4(wrow[k], arow[k]);
  float mu2  = block_sum(a2, red) * (1.f / C_);
  float d2   = a2 - mu2;
  float var2 = block_sum(d2 * d2, red) * (1.f / C_);
  float z = d2 * rsqrtf(var2 + LN_EPS) * twln_g[c] + twln_b[c];
  gate[n * C_ + c] = 1.f / (1.f + expf(-z));
}

// K5 x4: out = x * gate[n,c], float4 grid-stride, NT stores.
__global__ void k_scale_x4(const float* __restrict__ x, const float* __restrict__ gate,
                           float* __restrict__ out) {
  const f4* x4 = (const f4*)x;
  f4* o4 = (f4*)out;
  const int total = N_ * C_ * Q_;
  for (int rep = 0; rep < REPS; ++rep) {
    for (int i = blockIdx.x * blockDim.x + threadIdx.x; i < total;
         i += gridDim.x * blockDim.x) {
      int nc = i / Q_;
      float gv = gate[nc];
      f4 v = x4[i];
      v *= gv;
      __builtin_nontemporal_store(v, &o4[i]);
    }
    asm volatile("" ::: "memory");   // forbid cross-rep CSE; reps re-fetch
  }
}

extern "C" void kernel_launch(void* const* d_in, const int* in_sizes, int n_in,
                              void* d_out, int out_size, void* d_ws, size_t ws_size,
                              hipStream_t stream) {
  const float* x      = (const float*)d_in[0];
  const float* gc_w   = (const float*)d_in[1];
  // d_in[2] = gc_b: softmax shift-invariant, unused
  const float* lc_w   = (const float*)d_in[3];
  const float* lc_b   = (const float*)d_in[4];
  const float* lcln_g = (const float*)d_in[5];
  const float* lcln_b = (const float*)d_in[6];
  const float* tw_w   = (const float*)d_in[7];
  const float* tw_b   = (const float*)d_in[8];
  const float* twln_g = (const float*)d_in[9];
  const float* twln_b = (const float*)d_in[10];
  const float* wdct   = (const float*)d_in[11];
  const float* wmax   = (const float*)d_in[12];
  float* out = (float*)d_out;

  float* ws    = (float*)d_ws;
  float* lpart = ws;                                   // NCH*N*S
  float* attn  = lpart + (size_t)NCH * N_ * S_;        // N*S
  float* xg    = attn + (size_t)N_ * S_;               // N*C
  float* xmax_ = xg + N_ * C_;
  float* xdct_ = xmax_ + N_ * C_;
  float* gate  = xdct_ + N_ * C_;

  hipLaunchKernelGGL(k_logits_x4, dim3(NCH, N_, SQ), dim3(256), 0, stream, x, gc_w, lpart);
  hipLaunchKernelGGL(k_softmax, dim3(N_), dim3(256), 0, stream, lpart, attn);
  hipLaunchKernelGGL(k_stats, dim3(C_, N_), dim3(256), 0, stream, x, attn, xg, xmax_, xdct_);
  hipLaunchKernelGGL(k_gate, dim3(N_), dim3(256), 0, stream,
                     xg, xmax_, xdct_, lc_w, lc_b, lcln_g, lcln_b,
                     tw_w, tw_b, twln_g, twln_b, wdct, wmax, gate);
  hipLaunchKernelGGL(k_scale_x4, dim3(2048), dim3(256), 0, stream, x, gate, out);
}

// Round 11
// 87.666 us; speedup vs baseline: 2.0240x; 2.0240x over previous
//
#include <hip/hip_runtime.h>
#include <math.h>

// Channelatt: x(32,256,56,56) f32 -> x * sigmoid(gate(n,c))
// DIAGNOSTIC: k1 repeated 8x (idempotent) to surface its counters in top-5.
// k5 back to 1 rep (measured 30.7us in R10, near copy-roofline).
// Budget so far (measured/inferred): k1~40-50 (cold-read-bound?), k5~31,
// k2+k3+k4+gaps ~5-15.

#define N_ 32
#define C_ 256
#define H_ 56
#define W_ 56
#define S_ 3136   // H_*W_
#define Q_ 784    // S_/4 (float4 units)
#define LN_EPS 1e-5f

#define NCH 16    // c-chunks in pass 1
#define CPC 16    // channels per chunk (NCH*CPC == C_)
#define SQ  4     // s-chunks in pass 1
#define QCH 196   // f4 per s-chunk (Q_/SQ)
#define K1REPS 8  // diagnostic repeat factor for k1

using f4 = __attribute__((ext_vector_type(4))) float;

__device__ __forceinline__ float wave_sum(float v) {
  #pragma unroll
  for (int o = 32; o > 0; o >>= 1) v += __shfl_xor(v, o);
  return v;
}
__device__ __forceinline__ float wave_max(float v) {
  #pragma unroll
  for (int o = 32; o > 0; o >>= 1) v = fmaxf(v, __shfl_xor(v, o));
  return v;
}
__device__ __forceinline__ float block_sum(float v, float* red) {
  int lane = threadIdx.x & 63, wid = threadIdx.x >> 6;
  float w = wave_sum(v);
  __syncthreads();
  if (lane == 0) red[wid] = w;
  __syncthreads();
  return red[0] + red[1] + red[2] + red[3];
}
__device__ __forceinline__ float dot4(f4 a, f4 b) {
  return a.x * b.x + a.y * b.y + a.z * b.z + a.w * b.w;
}
__device__ __forceinline__ float max4(f4 a) {
  return fmaxf(fmaxf(a.x, a.y), fmaxf(a.z, a.w));
}

// K1 x8: partial logits. Block = (c-chunk, n, s-chunk) = 2048 blocks.
// No LDS/syncthreads: gc_w reads are block-uniform -> scalar path.
__global__ __launch_bounds__(256)
void k_logits_x8(const float* __restrict__ x, const float* __restrict__ gc_w,
                 float* __restrict__ lpart) {
  int ch = blockIdx.x, n = blockIdx.y, sq = blockIdx.z;
  int tid = threadIdx.x;
  int c0 = ch * CPC;
  if (tid >= QCH) return;
  int q = sq * QCH + tid;
  const f4* xb = (const f4*)x + ((size_t)n * C_ + c0) * Q_ + q;
  for (int rep = 0; rep < K1REPS; ++rep) {
    f4 A = {0,0,0,0};
    #pragma unroll
    for (int c = 0; c < CPC; ++c) A += gc_w[c0 + c] * xb[(size_t)c * Q_];
    ((f4*)lpart)[((size_t)n * NCH + ch) * Q_ + q] = A;
    asm volatile("" ::: "memory");   // forbid cross-rep CSE; reps re-fetch
  }
}

// K2: fold 16 partials -> softmax over s per n. One block per n, float4.
__global__ void k_softmax(const float* __restrict__ lpart, float* __restrict__ attn) {
  int n = blockIdx.x, tid = threadIdx.x;
  __shared__ float red[4];
  const f4* lp = (const f4*)lpart + (size_t)n * NCH * Q_;
  f4 v[4];
  float m = -INFINITY;
  #pragma unroll
  for (int k = 0; k < 3; ++k) {
    int q = tid + k * 256;
    f4 acc = {0,0,0,0};
    #pragma unroll
    for (int ch = 0; ch < NCH; ++ch) acc += lp[(size_t)ch * Q_ + q];
    v[k] = acc;
    m = fmaxf(m, max4(acc));
  }
  if (tid < 16) {
    f4 acc = {0,0,0,0};
    #pragma unroll
    for (int ch = 0; ch < NCH; ++ch) acc += lp[(size_t)ch * Q_ + 768 + tid];
    v[3] = acc;
    m = fmaxf(m, max4(acc));
  } else {
    v[3] = f4{-INFINITY, -INFINITY, -INFINITY, -INFINITY};
  }
  float wm = wave_max(m);
  int lane = tid & 63, wid = tid >> 6;
  if (lane == 0) red[wid] = wm;
  __syncthreads();
  m = fmaxf(fmaxf(red[0], red[1]), fmaxf(red[2], red[3]));
  float z = 0.f;
  #pragma unroll
  for (int k = 0; k < 4; ++k) {
    v[k].x = expf(v[k].x - m); v[k].y = expf(v[k].y - m);
    v[k].z = expf(v[k].z - m); v[k].w = expf(v[k].w - m);
    z += v[k].x + v[k].y + v[k].z + v[k].w;   // exp(-inf)=0 for tail lanes
  }
  z = block_sum(z, red);
  float inv = 1.f / z;
  f4* ap = (f4*)attn + (size_t)n * Q_;
  #pragma unroll
  for (int k = 0; k < 3; ++k) ap[tid + k * 256] = v[k] * inv;
  if (tid < 16) ap[768 + tid] = v[3] * inv;
}

// K3: per (n,c): x_g, x_max, x_dct in one warm x pass. Block per (c,n) = 8192.
__global__ void k_stats(const float* __restrict__ x, const float* __restrict__ attn,
                        float* __restrict__ xg, float* __restrict__ xmax,
                        float* __restrict__ xdct) {
  int c = blockIdx.x, n = blockIdx.y, tid = threadIdx.x;
  __shared__ float bh[H_];
  __shared__ f4 bw4[14];
  __shared__ float red[3][4];
  int grp = c >> 6;
  int u = grp >> 1, vv = grp & 1;
  const float invs = 0.13363062f;   // 1/sqrt(56)
  const float sq2  = 1.41421356f;
  if (tid < H_) {
    float b = cosf((float)M_PI * u * (tid + 0.5f) / H_) * invs;
    bh[tid] = u ? b * sq2 : b;
  } else if (tid >= 64 && tid < 64 + 14) {
    int j = tid - 64;
    f4 b;
    #pragma unroll
    for (int e = 0; e < 4; ++e) {
      float t = cosf((float)M_PI * vv * (4 * j + e + 0.5f) / W_) * invs;
      ((float*)&b)[e] = vv ? t * sq2 : t;
    }
    bw4[j] = b;
  }
  __syncthreads();
  const f4* xp = (const f4*)(x + ((size_t)n * C_ + c) * S_);
  const f4* ap = (const f4*)(attn + (size_t)n * S_);
  float g = 0.f, d = 0.f, mx = -INFINITY;
  #pragma unroll
  for (int k = 0; k < 3; ++k) {
    int q = tid + k * 256;
    f4 xv = xp[q], av = ap[q];
    g += dot4(xv, av);
    mx = fmaxf(max4(xv), mx);
    int h = q / 14;
    d += bh[h] * dot4(xv, bw4[q - h * 14]);
  }
  if (tid < 16) {
    int q = 768 + tid;
    f4 xv = xp[q], av = ap[q];
    g += dot4(xv, av);
    mx = fmaxf(max4(xv), mx);
    int h = q / 14;
    d += bh[h] * dot4(xv, bw4[q - h * 14]);
  }
  float gs = wave_sum(g), ms = wave_max(mx), ds = wave_sum(d);
  int lane = tid & 63, wid = tid >> 6;
  if (lane == 0) { red[0][wid] = gs; red[1][wid] = ms; red[2][wid] = ds; }
  __syncthreads();
  if (tid == 0) {
    xg[n * C_ + c]   = red[0][0] + red[0][1] + red[0][2] + red[0][3];
    xmax[n * C_ + c] = fmaxf(fmaxf(red[1][0], red[1][1]), fmaxf(red[1][2], red[1][3]));
    xdct[n * C_ + c] = red[2][0] + red[2][1] + red[2][2] + red[2][3];
  }
}

// K4: per-(n,c) gate math. One block per n, thread = channel.
__global__ void k_gate(const float* __restrict__ xg, const float* __restrict__ xmax,
                       const float* __restrict__ xdct,
                       const float* __restrict__ lc_w, const float* __restrict__ lc_b,
                       const float* __restrict__ lcln_g, const float* __restrict__ lcln_b,
                       const float* __restrict__ tw_w, const float* __restrict__ tw_b,
                       const float* __restrict__ twln_g, const float* __restrict__ twln_b,
                       const float* __restrict__ wdct, const float* __restrict__ wmax,
                       float* __restrict__ gate) {
  int n = blockIdx.x, c = threadIdx.x;
  __shared__ float xs[C_ + 2];
  __shared__ float att_s[C_];
  __shared__ float red[4];
  float g  = xg[n * C_ + c];
  float sv = wmax[c] * xmax[n * C_ + c] + wdct[c] * xdct[n * C_ + c];
  xs[c + 1] = sv;
  if (c == 0) { xs[0] = 0.f; xs[C_ + 1] = 0.f; }
  __syncthreads();
  float xl = lc_w[0] * xs[c] + lc_w[1] * xs[c + 1] + lc_w[2] * xs[c + 2] + lc_b[0];
  float t = g + sv + xl;
  float mu  = block_sum(t, red) * (1.f / C_);
  float dv  = t - mu;
  float var = block_sum(dv * dv, red) * (1.f / C_);
  float att = dv * rsqrtf(var + LN_EPS) * lcln_g[c] + lcln_b[c];
  att_s[c] = att;
  __syncthreads();
  float a2 = tw_b[c];
  const f4* wrow = (const f4*)(tw_w + c * C_);
  const f4* arow = (const f4*)att_s;
  #pragma unroll 8
  for (int k = 0; k < C_ / 4; ++k) a2 += dot4(wrow[k], arow[k]);
  float mu2  = block_sum(a2, red) * (1.f / C_);
  float d2   = a2 - mu2;
  float var2 = block_sum(d2 * d2, red) * (1.f / C_);
  float z = d2 * rsqrtf(var2 + LN_EPS) * twln_g[c] + twln_b[c];
  gate[n * C_ + c] = 1.f / (1.f + expf(-z));
}

// K5: out = x * gate[n,c], float4 grid-stride, NT stores.
__global__ void k_scale(const float* __restrict__ x, const float* __restrict__ gate,
                        float* __restrict__ out) {
  const f4* x4 = (const f4*)x;
  f4* o4 = (f4*)out;
  const int total = N_ * C_ * Q_;
  for (int i = blockIdx.x * blockDim.x + threadIdx.x; i < total;
       i += gridDim.x * blockDim.x) {
    int nc = i / Q_;
    float gv = gate[nc];
    f4 v = x4[i];
    v *= gv;
    __builtin_nontemporal_store(v, &o4[i]);
  }
}

extern "C" void kernel_launch(void* const* d_in, const int* in_sizes, int n_in,
                              void* d_out, int out_size, void* d_ws, size_t ws_size,
                              hipStream_t stream) {
  const float* x      = (const float*)d_in[0];
  const float* gc_w   = (const float*)d_in[1];
  // d_in[2] = gc_b: softmax shift-invariant, unused
  const float* lc_w   = (const float*)d_in[3];
  const float* lc_b   = (const float*)d_in[4];
  const float* lcln_g = (const float*)d_in[5];
  const float* lcln_b = (const float*)d_in[6];
  const float* tw_w   = (const float*)d_in[7];
  const float* tw_b   = (const float*)d_in[8];
  const float* twln_g = (const float*)d_in[9];
  const float* twln_b = (const float*)d_in[10];
  const float* wdct   = (const float*)d_in[11];
  const float* wmax   = (const float*)d_in[12];
  float* out = (float*)d_out;

  float* ws    = (float*)d_ws;
  float* lpart = ws;                                   // NCH*N*S
  float* attn  = lpart + (size_t)NCH * N_ * S_;        // N*S
  float* xg    = attn + (size_t)N_ * S_;               // N*C
  float* xmax_ = xg + N_ * C_;
  float* xdct_ = xmax_ + N_ * C_;
  float* gate  = xdct_ + N_ * C_;

  hipLaunchKernelGGL(k_logits_x8, dim3(NCH, N_, SQ), dim3(256), 0, stream, x, gc_w, lpart);
  hipLaunchKernelGGL(k_softmax, dim3(N_), dim3(256), 0, stream, lpart, attn);
  hipLaunchKernelGGL(k_stats, dim3(C_, N_), dim3(256), 0, stream, x, attn, xg, xmax_, xdct_);
  hipLaunchKernelGGL(k_gate, dim3(N_), dim3(256), 0, stream,
                     xg, xmax_, xdct_, lc_w, lc_b, lcln_g, lcln_b,
                     tw_w, tw_b, twln_g, twln_b, wdct, wmax, gate);
  hipLaunchKernelGGL(k_scale, dim3(2048), dim3(256), 0, stream, x, gate, out);
}